// Round 2
// baseline (1234.913 us; speedup 1.0000x reference)
//
#include <hip/hip_runtime.h>
#include <math.h>

// Problem constants (B,S,D,H fixed by the reference)
constexpr int B  = 2;
constexpr int S  = 2048;
constexpr int D  = 1024;
constexpr int H  = 16;
constexpr int DK = 64;
constexpr int M  = B * S;  // 4096 rows for the projection GEMMs

// ---------------------------------------------------------------------------
// proj_gemm: Out = X @ W^T + bias      X:[M,D], W:[N=D,D] (row n = out col n)
// outMode 0: write [B,H,S,DK] layout with RoPE applied
// outMode 1: write [B,H,S,DK] layout, no RoPE (V projection)
// outMode 2: write plain [M,D] (output projection -> d_out)
// 128x128 tile, BK=16, 256 threads, 8x8 per-thread microtile. fp32 VALU.
// ---------------------------------------------------------------------------
#define BM 128
#define BN 128
#define BKK 16

__global__ __launch_bounds__(256, 2) void proj_gemm(
    const float* __restrict__ X, const float* __restrict__ W,
    const float* __restrict__ bias, float* __restrict__ Out, const int outMode)
{
  // +4 pad keeps rows 16B-aligned (132 floats = 33*16B) and breaks bank strides
  __shared__ float As[BKK][BM + 4];   // As[k][m]
  __shared__ float Bs[BKK][BN + 4];   // Bs[k][n]

  const int tid  = threadIdx.x;
  const int tx   = tid & 15;    // output col group
  const int ty   = tid >> 4;    // output row group
  const int row0 = blockIdx.x * BM;
  const int col0 = blockIdx.y * BN;

  float acc[8][8];
#pragma unroll
  for (int i = 0; i < 8; ++i) {
#pragma unroll
    for (int j = 0; j < 8; ++j) acc[i][j] = 0.f;
  }

  const int lr = tid >> 2;         // 0..63 : tile row for loads
  const int lc = (tid & 3) << 2;   // 0,4,8,12 : k-col start (float4)

  for (int k0 = 0; k0 < D; k0 += BKK) {
    // stage A (128x16) and B (128x16), transposed into [k][m] / [k][n]
#pragma unroll
    for (int hh = 0; hh < 2; ++hh) {
      const int r = lr + hh * 64;
      const float4 va = *reinterpret_cast<const float4*>(&X[(size_t)(row0 + r) * D + k0 + lc]);
      As[lc + 0][r] = va.x; As[lc + 1][r] = va.y; As[lc + 2][r] = va.z; As[lc + 3][r] = va.w;
      const float4 vb = *reinterpret_cast<const float4*>(&W[(size_t)(col0 + r) * D + k0 + lc]);
      Bs[lc + 0][r] = vb.x; Bs[lc + 1][r] = vb.y; Bs[lc + 2][r] = vb.z; Bs[lc + 3][r] = vb.w;
    }
    __syncthreads();

#pragma unroll
    for (int kk = 0; kk < BKK; ++kk) {
      float a[8], bb[8];
      *reinterpret_cast<float4*>(&a[0])  = *reinterpret_cast<const float4*>(&As[kk][ty * 8]);
      *reinterpret_cast<float4*>(&a[4])  = *reinterpret_cast<const float4*>(&As[kk][ty * 8 + 4]);
      *reinterpret_cast<float4*>(&bb[0]) = *reinterpret_cast<const float4*>(&Bs[kk][tx * 8]);
      *reinterpret_cast<float4*>(&bb[4]) = *reinterpret_cast<const float4*>(&Bs[kk][tx * 8 + 4]);
#pragma unroll
      for (int i = 0; i < 8; ++i) {
#pragma unroll
        for (int j = 0; j < 8; ++j) acc[i][j] = fmaf(a[i], bb[j], acc[i][j]);
      }
    }
    __syncthreads();
  }

  // epilogue: bias (+ optional RoPE) + scatter
#pragma unroll
  for (int i = 0; i < 8; ++i) {
    const int row  = row0 + ty * 8 + i;
    const int bidx = row >> 11;        // /S
    const int srow = row & (S - 1);
#pragma unroll
    for (int j = 0; j < 8; ++j) {
      const int n = col0 + tx * 8 + j;
      float v = acc[i][j] + bias[n];
      if (outMode == 2) {
        Out[(size_t)row * D + n] = v;
      } else {
        const int hh = n >> 6;
        const int dk = n & 63;
        if (outMode == 0) {
          // RoPE: partner element dk^32 lives on lane tx^4 (same j)
          const float partner = __shfl_xor(v, 4, 64);
          const float rot = (dk < 32) ? -partner : partner;
          const int jj = dk & 31;
          // inv_freq = 10000^(-jj/32) computed as exp2(-jj*log2(10000)/32)
          const float ang = (float)srow * exp2f(-(float)jj * (13.287712379549449f / 32.0f));
          float cs, sn;
          sincosf(ang, &sn, &cs);   // sincosf(x, sin*, cos*) -- sin is FIRST
          v = v * cs + rot * sn;
        }
        Out[(((size_t)(bidx * H + hh) * S) + srow) * DK + dk] = v;
      }
    }
  }
}

// ---------------------------------------------------------------------------
// attn_fused: causal flash attention, fp32. One workgroup = one (b*h, q-tile).
// 64x64 tiles, 256 threads, 4x4 microtile, online softmax with shuffle
// reductions across the 16 lanes that share a q-row.
// ---------------------------------------------------------------------------
__global__ __launch_bounds__(256, 2) void attn_fused(
    const float* __restrict__ Q, const float* __restrict__ K,
    const float* __restrict__ V, float* __restrict__ Xo)
{
  __shared__ float Qs[64][68];  // Qs[dk][row]  (transposed)
  __shared__ float Ks[64][68];  // Ks[dk][col]  (transposed)
  __shared__ float Vs[64][68];  // Vs[col][dk]  (row-major)
  __shared__ float Ps[64][68];  // Ps[col][row] (transposed P)

  const int tid = threadIdx.x;
  const int tx  = tid & 15;   // k-col / dk group
  const int ty  = tid >> 4;   // q-row group
  const int qt  = gridDim.x - 1 - blockIdx.x;  // reversed: heavy tiles first
  const int bh  = blockIdx.y;
  const size_t base = (size_t)bh * S * DK;
  const int q0 = qt * 64;

  // stage Q tile transposed (lives for the whole kernel)
#pragma unroll
  for (int it = 0; it < 4; ++it) {
    const int r = (tid >> 4) + it * 16;
    const int c = (tid & 15) << 2;
    const float4 v = *reinterpret_cast<const float4*>(&Q[base + (size_t)(q0 + r) * DK + c]);
    Qs[c + 0][r] = v.x; Qs[c + 1][r] = v.y; Qs[c + 2][r] = v.z; Qs[c + 3][r] = v.w;
  }

  float acc[4][4];
  float mrow[4], lrow[4];
#pragma unroll
  for (int i = 0; i < 4; ++i) {
    mrow[i] = -INFINITY;
    lrow[i] = 0.f;
#pragma unroll
    for (int j = 0; j < 4; ++j) acc[i][j] = 0.f;
  }

  for (int kt = 0; kt <= qt; ++kt) {
    const int k0 = kt * 64;
    __syncthreads();  // previous iteration's readers of Ks/Vs are done; Qs ready (1st iter)
#pragma unroll
    for (int it = 0; it < 4; ++it) {
      const int r = (tid >> 4) + it * 16;
      const int c = (tid & 15) << 2;
      const float4 kv = *reinterpret_cast<const float4*>(&K[base + (size_t)(k0 + r) * DK + c]);
      Ks[c + 0][r] = kv.x; Ks[c + 1][r] = kv.y; Ks[c + 2][r] = kv.z; Ks[c + 3][r] = kv.w;
      const float4 vv = *reinterpret_cast<const float4*>(&V[base + (size_t)(k0 + r) * DK + c]);
      *reinterpret_cast<float4*>(&Vs[r][c]) = vv;
    }
    __syncthreads();

    // S_tile = Q K^T
    float sc[4][4];
#pragma unroll
    for (int i = 0; i < 4; ++i)
#pragma unroll
      for (int j = 0; j < 4; ++j) sc[i][j] = 0.f;

#pragma unroll 8
    for (int kk = 0; kk < 64; ++kk) {
      float a[4], bb[4];
      *reinterpret_cast<float4*>(&a[0])  = *reinterpret_cast<const float4*>(&Qs[kk][ty * 4]);
      *reinterpret_cast<float4*>(&bb[0]) = *reinterpret_cast<const float4*>(&Ks[kk][tx * 4]);
#pragma unroll
      for (int i = 0; i < 4; ++i)
#pragma unroll
        for (int j = 0; j < 4; ++j) sc[i][j] = fmaf(a[i], bb[j], sc[i][j]);
    }

    // scale + causal mask (match reference: masked = -1e9 before softmax)
    const bool diag = (kt == qt);
    float rm[4];
#pragma unroll
    for (int i = 0; i < 4; ++i) {
      rm[i] = -INFINITY;
#pragma unroll
      for (int j = 0; j < 4; ++j) {
        float sv = sc[i][j] * 0.125f;   // 1/sqrt(64)
        if (diag && (tx * 4 + j) > (ty * 4 + i)) sv = -1e9f;
        sc[i][j] = sv;
        rm[i] = fmaxf(rm[i], sv);
      }
    }
    // row-max across the 16 lanes sharing each q-row
#pragma unroll
    for (int off = 1; off < 16; off <<= 1) {
#pragma unroll
      for (int i = 0; i < 4; ++i) rm[i] = fmaxf(rm[i], __shfl_xor(rm[i], off, 64));
    }

    float p[4][4], rs[4];
#pragma unroll
    for (int i = 0; i < 4; ++i) {
      const float mnew = fmaxf(mrow[i], rm[i]);
      const float corr = __expf(mrow[i] - mnew);  // 0 on first tile (-inf - finite)
      mrow[i] = mnew;
      lrow[i] *= corr;
      rs[i] = 0.f;
#pragma unroll
      for (int j = 0; j < 4; ++j) {
        p[i][j] = __expf(sc[i][j] - mnew);
        rs[i] += p[i][j];
        acc[i][j] *= corr;
      }
    }
#pragma unroll
    for (int off = 1; off < 16; off <<= 1) {
#pragma unroll
      for (int i = 0; i < 4; ++i) rs[i] += __shfl_xor(rs[i], off, 64);
    }
#pragma unroll
    for (int i = 0; i < 4; ++i) lrow[i] += rs[i];

    // store P transposed for the PV pass
#pragma unroll
    for (int i = 0; i < 4; ++i)
#pragma unroll
      for (int j = 0; j < 4; ++j) Ps[tx * 4 + j][ty * 4 + i] = p[i][j];
    __syncthreads();

    // acc += P @ V
#pragma unroll 8
    for (int c = 0; c < 64; ++c) {
      float a[4], bb[4];
      *reinterpret_cast<float4*>(&a[0])  = *reinterpret_cast<const float4*>(&Ps[c][ty * 4]);
      *reinterpret_cast<float4*>(&bb[0]) = *reinterpret_cast<const float4*>(&Vs[c][tx * 4]);
#pragma unroll
      for (int i = 0; i < 4; ++i)
#pragma unroll
        for (int j = 0; j < 4; ++j) acc[i][j] = fmaf(a[i], bb[j], acc[i][j]);
    }
  }

  // normalize + write x in [B,S,D] layout (heads concatenated)
  const int bidx = bh >> 4;
  const int hh   = bh & 15;
#pragma unroll
  for (int i = 0; i < 4; ++i) {
    const int srow = q0 + ty * 4 + i;
    const float inv = 1.0f / lrow[i];
#pragma unroll
    for (int j = 0; j < 4; ++j) {
      const int col = hh * DK + tx * 4 + j;
      Xo[((size_t)bidx * S + srow) * D + col] = acc[i][j] * inv;
    }
  }
}

// ---------------------------------------------------------------------------
extern "C" void kernel_launch(void* const* d_in, const int* in_sizes, int n_in,
                              void* d_out, int out_size, void* d_ws, size_t ws_size,
                              hipStream_t stream) {
  const float* query = (const float*)d_in[0];
  const float* key   = (const float*)d_in[1];
  const float* value = (const float*)d_in[2];
  // d_in[3] = mask (causal, known statically) -- unused
  const float* Wq = (const float*)d_in[4];
  const float* bq = (const float*)d_in[5];
  const float* Wk = (const float*)d_in[6];
  const float* bk = (const float*)d_in[7];
  const float* Wv = (const float*)d_in[8];
  const float* bv = (const float*)d_in[9];
  const float* Wo = (const float*)d_in[10];
  const float* bo = (const float*)d_in[11];
  float* out = (float*)d_out;

  // workspace: Q,K,V in [B,H,S,DK] + attention output x in [B,S,D] (64 MB total)
  const size_t per = (size_t)B * H * S * DK;  // 4 Mi floats
  float* Qb = (float*)d_ws;
  float* Kb = Qb + per;
  float* Vb = Kb + per;
  float* Xb = Vb + per;

  const dim3 ggrid(M / BM, D / BN);  // 32 x 8
  proj_gemm<<<ggrid, 256, 0, stream>>>(query, Wq, bq, Qb, 0);  // Q + RoPE
  proj_gemm<<<ggrid, 256, 0, stream>>>(key,   Wk, bk, Kb, 0);  // K + RoPE
  proj_gemm<<<ggrid, 256, 0, stream>>>(value, Wv, bv, Vb, 1);  // V
  attn_fused<<<dim3(S / 64, B * H), 256, 0, stream>>>(Qb, Kb, Vb, Xb);
  proj_gemm<<<ggrid, 256, 0, stream>>>(Xb, Wo, bo, out, 2);    // out proj
}

// Round 4
// 929.143 us; speedup vs baseline: 1.3291x; 1.3291x over previous
//
#include <hip/hip_runtime.h>
#include <math.h>

typedef unsigned short u16;
typedef unsigned int u32;
typedef __attribute__((ext_vector_type(4))) float f32x4;
typedef __attribute__((ext_vector_type(4))) short bf16x4;
typedef __attribute__((ext_vector_type(8))) short bf16x8;
typedef __attribute__((ext_vector_type(8))) unsigned short u16x8;

constexpr int Bc = 2, Sc = 2048, Dc = 1024, Hc = 16, DKc = 64, Mc = 4096;

__device__ __forceinline__ u16 f2bf(float f) {
  union { float f; u32 u; } v; v.f = f;
  u32 r = v.u + 0x7FFFu + ((v.u >> 16) & 1u);   // round-to-nearest-even
  return (u16)(r >> 16);
}

__device__ __forceinline__ void gll16(const u16* g, const u16* l) {
  __builtin_amdgcn_global_load_lds((const __attribute__((address_space(1))) void*)g,
                                   (__attribute__((address_space(3))) void*)l, 16, 0, 0);
}

// MFMA 16x16x32 bf16 A/B fragment: elem j -> k = 16*(j>>2) + 4*(lane>>4) + (j&3)
// i.e. two bf16x4 groups 16 k apart (matches ds_read_b64_tr_b16 lane layout, m162).
__device__ __forceinline__ bf16x8 load_frag(const u16* p) {
  bf16x4 lo = *(const bf16x4*)p;        // k = base + 4*l4 .. +3
  bf16x4 hi = *(const bf16x4*)(p + 16); // k = base + 16 + 4*l4 .. +3
  return __builtin_shufflevector(lo, hi, 0, 1, 2, 3, 4, 5, 6, 7);
}

// ---------------------------------------------------------------------------
__global__ __launch_bounds__(256) void cast_bf16(const float* __restrict__ in,
                                                 u16* __restrict__ out, int n8) {
  const int i = blockIdx.x * 256 + threadIdx.x;
  if (i >= n8) return;
  const float4* p = (const float4*)in + (size_t)i * 2;
  const float4 a = p[0], b = p[1];
  u16x8 o;
  o[0] = f2bf(a.x); o[1] = f2bf(a.y); o[2] = f2bf(a.z); o[3] = f2bf(a.w);
  o[4] = f2bf(b.x); o[5] = f2bf(b.y); o[6] = f2bf(b.z); o[7] = f2bf(b.w);
  ((u16x8*)out)[i] = o;
}

// ---------------------------------------------------------------------------
// gemm_bf16: Out = X @ W^T + bias. X:[4096][1024] bf16, W:[1024][1024] bf16.
// 128x128 tile, BK=64, 512 threads (8 waves, 4x2 grid; wave tile 32x64).
// MODE 0: +RoPE -> bf16 [B,H,S,DK]; MODE 1: -> bf16 [B,H,DK,S] (transposed);
// MODE 2: -> fp32 [M][D].
// ---------------------------------------------------------------------------
template <int MODE>
__global__ __launch_bounds__(512) void gemm_bf16(
    const u16* __restrict__ X, const u16* __restrict__ W,
    const float* __restrict__ bias, void* __restrict__ OutP)
{
  __shared__ u16 smem[4 * 128 * 64];           // A0 A1 B0 B1, 16KB each

  const int tid = threadIdx.x;
  const int w = tid >> 6, lane = tid & 63;
  const int l15 = lane & 15, l4 = lane >> 4;
  const int wr = w >> 1, wc = w & 1;           // 4x2 wave grid
  const int row0 = blockIdx.x * 128;
  const int col0 = blockIdx.y * 128;

  f32x4 acc[2][4] = {};

  auto stage = [&](int buf, int k0) {
    u16* dA = smem + buf * 8192;
    u16* dB = smem + 16384 + buf * 8192;
#pragma unroll
    for (int s = 0; s < 2; ++s) {
      const int c = s * 512 + w * 64 + lane;   // chunk 0..1023
      const int r = c >> 3, cc = c & 7;
      gll16(X + (size_t)(row0 + r) * Dc + k0 + cc * 8, dA + (s * 512 + w * 64) * 8);
      gll16(W + (size_t)(col0 + r) * Dc + k0 + cc * 8, dB + (s * 512 + w * 64) * 8);
    }
  };

  stage(0, 0);
  __syncthreads();

  for (int kt = 0; kt < Dc / 64; ++kt) {
    const int cur = kt & 1;
    if (kt + 1 < Dc / 64) stage(cur ^ 1, (kt + 1) * 64);
    const u16* At = smem + cur * 8192;
    const u16* Bt = smem + 16384 + cur * 8192;
#pragma unroll
    for (int ks = 0; ks < 2; ++ks) {
      bf16x8 af[2], bfr[4];
#pragma unroll
      for (int m = 0; m < 2; ++m)
        af[m] = load_frag(&At[(wr * 32 + m * 16 + l15) * 64 + ks * 32 + l4 * 4]);
#pragma unroll
      for (int n = 0; n < 4; ++n)
        bfr[n] = load_frag(&Bt[(wc * 64 + n * 16 + l15) * 64 + ks * 32 + l4 * 4]);
#pragma unroll
      for (int m = 0; m < 2; ++m)
#pragma unroll
        for (int n = 0; n < 4; ++n)
          acc[m][n] = __builtin_amdgcn_mfma_f32_16x16x32_bf16(af[m], bfr[n], acc[m][n], 0, 0, 0);
    }
    __syncthreads();
  }

  // epilogue --------------------------------------------------------------
  if constexpr (MODE == 2) {
    float* Out = (float*)OutP;
#pragma unroll
    for (int m = 0; m < 2; ++m)
#pragma unroll
      for (int i = 0; i < 4; ++i) {
        const int row = row0 + wr * 32 + m * 16 + 4 * l4 + i;
#pragma unroll
        for (int n = 0; n < 4; ++n) {
          const int col = col0 + wc * 64 + n * 16 + l15;
          Out[(size_t)row * Dc + col] = acc[m][n][i] + bias[col];
        }
      }
  } else if constexpr (MODE == 0) {
    u16* Out = (u16*)OutP;
    const int h = (col0 >> 6) + wc;            // global head
#pragma unroll
    for (int m = 0; m < 2; ++m)
#pragma unroll
      for (int i = 0; i < 4; ++i) {
        const int row = row0 + wr * 32 + m * 16 + 4 * l4 + i;
        const int srow = row & (Sc - 1);
        const size_t obase = ((size_t)((row >> 11) * Hc + h) * Sc + srow) * DKc;
        float vv[4];
#pragma unroll
        for (int n = 0; n < 4; ++n)
          vv[n] = acc[m][n][i] + bias[col0 + wc * 64 + n * 16 + l15];
        float cs[2], sn[2];
#pragma unroll
        for (int hf = 0; hf < 2; ++hf) {
          const int jj = hf * 16 + l15;        // dk & 31
          const float ang = (float)srow * exp2f((float)jj * (-13.287712379549449f / 32.0f));
          sincosf(ang, &sn[hf], &cs[hf]);      // sin FIRST
        }
#pragma unroll
        for (int n = 0; n < 4; ++n) {
          // dk = n*16 + l15; partner dk^32 -> n^2, same thread
          const float rot = (n < 2) ? -vv[n ^ 2] : vv[n ^ 2];
          const float o = vv[n] * cs[n & 1] + rot * sn[n & 1];
          Out[obase + n * 16 + l15] = f2bf(o);
        }
      }
  } else {  // MODE 1: V -> [B,H,DK,S] via LDS transpose (coalesced out)
    u16* Out = (u16*)OutP;
    u16* T = smem;                              // [128 c][132 r], 33 KB
    __syncthreads();                            // all MFMA LDS reads done before reuse
#pragma unroll
    for (int m = 0; m < 2; ++m)
#pragma unroll
      for (int i = 0; i < 4; ++i) {
        const int r = wr * 32 + m * 16 + 4 * l4 + i;
#pragma unroll
        for (int n = 0; n < 4; ++n) {
          const int c = wc * 64 + n * 16 + l15;
          T[c * 132 + r] = f2bf(acc[m][n][i] + bias[col0 + c]);
        }
      }
    __syncthreads();
    const int bidx = row0 >> 11, srow0 = row0 & (Sc - 1);
    const int c = tid >> 2, rq = (tid & 3) * 32;
    const int h = (col0 >> 6) + (c >> 6);
    const int dk = c & 63;
    u16* gdst = Out + ((size_t)(bidx * Hc + h) * DKc + dk) * Sc + srow0 + rq;
#pragma unroll
    for (int u = 0; u < 4; ++u)
      *(u16x8*)(gdst + u * 8) = *(const u16x8*)&T[c * 132 + rq + u * 8];
  }
}

// ---------------------------------------------------------------------------
// attn_mfma: causal flash attention, bf16 MFMA. QBLK=128 (4 waves x 32 rows),
// KVBLK=64, double-buffered K/V staging via global_load_lds.
// Q,K: [B,H,S,64] bf16; Vt: [B,H,64,S] bf16; out Xb: [B,S,1024] bf16.
// ---------------------------------------------------------------------------
__global__ __launch_bounds__(256) void attn_mfma(
    const u16* __restrict__ Qb, const u16* __restrict__ Kb,
    const u16* __restrict__ Vt, u16* __restrict__ Xb)
{
  __shared__ u16 smem[32768];                  // 64 KB
  // layout: Qs [128][64] @0; K bufs @8192+buf*4096; V bufs @16384+buf*4096;
  //         Ps [128][64] @24576
  u16* Qs = smem;
  u16* Ps = smem + 24576;

  const int tid = threadIdx.x;
  const int w = tid >> 6, lane = tid & 63;
  const int l15 = lane & 15, l4 = lane >> 4;
  const int qt = gridDim.x - 1 - blockIdx.x;   // heavy q-tiles first
  const int bh = blockIdx.y;
  const int q0 = qt * 128;
  const u16* Qg = Qb + ((size_t)bh * Sc + q0) * DKc;
  const u16* Kg = Kb + (size_t)bh * Sc * DKc;
  const u16* Vg = Vt + (size_t)bh * DKc * Sc;

  // stage Q (1024 chunks, 4 per thread)
#pragma unroll
  for (int s = 0; s < 4; ++s) {
    const int c = s * 256 + w * 64 + lane;
    const int r = c >> 3, cc = c & 7;
    gll16(Qg + (size_t)r * DKc + cc * 8, Qs + (s * 256 + w * 64) * 8);
  }
  auto stageKV = [&](int buf, int k0) {
    u16* Kd = smem + 8192 + buf * 4096;
    u16* Vd = smem + 16384 + buf * 4096;
#pragma unroll
    for (int s = 0; s < 2; ++s) {
      const int c = s * 256 + w * 64 + lane;   // 0..511
      const int r = c >> 3, cc = c & 7;
      gll16(Kg + (size_t)(k0 + r) * DKc + cc * 8, Kd + (s * 256 + w * 64) * 8);
      gll16(Vg + (size_t)r * Sc + k0 + cc * 8,   Vd + (s * 256 + w * 64) * 8);
    }
  };
  stageKV(0, 0);
  __syncthreads();

  f32x4 aco[2][4] = {};
  float mrow[2][4], lrow[2][4];
#pragma unroll
  for (int m = 0; m < 2; ++m)
#pragma unroll
    for (int i = 0; i < 4; ++i) { mrow[m][i] = -INFINITY; lrow[m][i] = 0.f; }

  const int nk = 2 * qt + 2;
  for (int kt = 0; kt < nk; ++kt) {
    const int cur = kt & 1;
    if (kt + 1 < nk) stageKV(cur ^ 1, (kt + 1) * 64);
    const u16* Kt = smem + 8192 + cur * 4096;
    const u16* Vc = smem + 16384 + cur * 4096;

    // S = Q K^T (wave's 32 q-rows x 64 k-cols)
    f32x4 acs[2][4] = {};
#pragma unroll
    for (int ks = 0; ks < 2; ++ks) {
      bf16x8 aq[2], bk[4];
#pragma unroll
      for (int m = 0; m < 2; ++m)
        aq[m] = load_frag(&Qs[(w * 32 + m * 16 + l15) * 64 + ks * 32 + l4 * 4]);
#pragma unroll
      for (int n = 0; n < 4; ++n)
        bk[n] = load_frag(&Kt[(n * 16 + l15) * 64 + ks * 32 + l4 * 4]);
#pragma unroll
      for (int m = 0; m < 2; ++m)
#pragma unroll
        for (int n = 0; n < 4; ++n)
          acs[m][n] = __builtin_amdgcn_mfma_f32_16x16x32_bf16(aq[m], bk[n], acs[m][n], 0, 0, 0);
    }

    // online softmax (rows: q = q0 + w*32 + m*16 + 4*l4 + i; cols: n*16 + l15)
    const bool mtile = (kt >= 2 * qt);
    const int k0 = kt * 64;
#pragma unroll
    for (int m = 0; m < 2; ++m)
#pragma unroll
      for (int i = 0; i < 4; ++i) {
        const int q = q0 + w * 32 + m * 16 + 4 * l4 + i;
        float sv[4], rm = -INFINITY;
#pragma unroll
        for (int n = 0; n < 4; ++n) {
          sv[n] = acs[m][n][i] * 0.125f;
          if (mtile && (k0 + n * 16 + l15) > q) sv[n] = -1e9f;
          rm = fmaxf(rm, sv[n]);
        }
#pragma unroll
        for (int off = 1; off < 16; off <<= 1) rm = fmaxf(rm, __shfl_xor(rm, off, 64));
        const float mnew = fmaxf(mrow[m][i], rm);
        const float corr = __expf(mrow[m][i] - mnew);
        mrow[m][i] = mnew;
        float p[4], rs = 0.f;
#pragma unroll
        for (int n = 0; n < 4; ++n) { p[n] = __expf(sv[n] - mnew); rs += p[n]; }
#pragma unroll
        for (int off = 1; off < 16; off <<= 1) rs += __shfl_xor(rs, off, 64);
        lrow[m][i] = lrow[m][i] * corr + rs;
#pragma unroll
        for (int n = 0; n < 4; ++n) {
          aco[m][n][i] *= corr;
          Ps[(w * 32 + m * 16 + 4 * l4 + i) * 64 + n * 16 + l15] = f2bf(p[n]);
        }
      }

    // O += P V  (A = Ps rows (wave-private), B = Vs: B[k=c][d])
#pragma unroll
    for (int ks = 0; ks < 2; ++ks) {
      bf16x8 pa[2], bv[4];
#pragma unroll
      for (int m = 0; m < 2; ++m)
        pa[m] = load_frag(&Ps[(w * 32 + m * 16 + l15) * 64 + ks * 32 + l4 * 4]);
#pragma unroll
      for (int n = 0; n < 4; ++n)
        bv[n] = load_frag(&Vc[(n * 16 + l15) * 64 + ks * 32 + l4 * 4]);
#pragma unroll
      for (int m = 0; m < 2; ++m)
#pragma unroll
        for (int n = 0; n < 4; ++n)
          aco[m][n] = __builtin_amdgcn_mfma_f32_16x16x32_bf16(pa[m], bv[n], aco[m][n], 0, 0, 0);
    }
    __syncthreads();
  }

  // epilogue: x[b, q, h*64+dk] = O/l
  const int bidx = bh >> 4, h = bh & 15;
#pragma unroll
  for (int m = 0; m < 2; ++m)
#pragma unroll
    for (int i = 0; i < 4; ++i) {
      const int q = q0 + w * 32 + m * 16 + 4 * l4 + i;
      const float inv = 1.0f / lrow[m][i];
#pragma unroll
      for (int n = 0; n < 4; ++n)
        Xb[((size_t)bidx * Sc + q) * Dc + h * DKc + n * 16 + l15] = f2bf(aco[m][n][i] * inv);
    }
}

// ---------------------------------------------------------------------------
extern "C" void kernel_launch(void* const* d_in, const int* in_sizes, int n_in,
                              void* d_out, int out_size, void* d_ws, size_t ws_size,
                              hipStream_t stream) {
  const float* query = (const float*)d_in[0];
  const float* key   = (const float*)d_in[1];
  const float* value = (const float*)d_in[2];
  const float* Wq = (const float*)d_in[4];
  const float* bq = (const float*)d_in[5];
  const float* Wk = (const float*)d_in[6];
  const float* bk = (const float*)d_in[7];
  const float* Wv = (const float*)d_in[8];
  const float* bv = (const float*)d_in[9];
  const float* Wo = (const float*)d_in[10];
  const float* bo = (const float*)d_in[11];

  const size_t MD = (size_t)Mc * Dc;   // 4M
  const size_t DD = (size_t)Dc * Dc;   // 1M
  u16* xq = (u16*)d_ws;
  u16* xk = xq + MD;
  u16* xv = xk + MD;
  u16* wq = xv + MD;
  u16* wk = wq + DD;
  u16* wv = wk + DD;
  u16* wo = wv + DD;
  u16* Qb = wo + DD;
  u16* Kb = Qb + MD;
  u16* Vt = Kb + MD;
  u16* Xb = Vt + MD;   // total 64 MB

  cast_bf16<<<dim3(MD / 2048), 256, 0, stream>>>(query, xq, (int)(MD / 8));
  cast_bf16<<<dim3(MD / 2048), 256, 0, stream>>>(key,   xk, (int)(MD / 8));
  cast_bf16<<<dim3(MD / 2048), 256, 0, stream>>>(value, xv, (int)(MD / 8));
  cast_bf16<<<dim3(DD / 2048), 256, 0, stream>>>(Wq, wq, (int)(DD / 8));
  cast_bf16<<<dim3(DD / 2048), 256, 0, stream>>>(Wk, wk, (int)(DD / 8));
  cast_bf16<<<dim3(DD / 2048), 256, 0, stream>>>(Wv, wv, (int)(DD / 8));
  cast_bf16<<<dim3(DD / 2048), 256, 0, stream>>>(Wo, wo, (int)(DD / 8));

  const dim3 gg(Mc / 128, Dc / 128);   // 32 x 8
  gemm_bf16<0><<<gg, 512, 0, stream>>>(xq, wq, bq, Qb);
  gemm_bf16<0><<<gg, 512, 0, stream>>>(xk, wk, bk, Kb);
  gemm_bf16<1><<<gg, 512, 0, stream>>>(xv, wv, bv, Vt);
  attn_mfma<<<dim3(Sc / 128, Bc * Hc), 256, 0, stream>>>(Qb, Kb, Vt, Xb);
  gemm_bf16<2><<<gg, 512, 0, stream>>>(Xb, wo, bo, d_out);
}

// Round 5
// 307.671 us; speedup vs baseline: 4.0137x; 3.0199x over previous
//
#include <hip/hip_runtime.h>
#include <math.h>

typedef unsigned short u16;
typedef unsigned int u32;
typedef __attribute__((ext_vector_type(4))) float f32x4;
typedef __attribute__((ext_vector_type(4))) short bf16x4;
typedef __attribute__((ext_vector_type(8))) short bf16x8;
typedef __attribute__((ext_vector_type(8))) unsigned short u16x8;

constexpr int Bc = 2, Sc = 2048, Dc = 1024, Hc = 16, DKc = 64, Mc = 4096;

__device__ __forceinline__ u16 f2bf(float f) {
  union { float f; u32 u; } v; v.f = f;
  u32 r = v.u + 0x7FFFu + ((v.u >> 16) & 1u);   // round-to-nearest-even
  return (u16)(r >> 16);
}

__device__ __forceinline__ void gll16(const u16* g, const u16* l) {
  __builtin_amdgcn_global_load_lds((const __attribute__((address_space(1))) void*)g,
                                   (__attribute__((address_space(3))) void*)l, 16, 0, 0);
}

// ---------------------------------------------------------------------------
// All LDS tiles are [R rows][64 cols] u16 (128-B rows). Unswizzled, frag reads
// put 16 lanes on 16 rows at one column -> 16-way bank conflict. XOR swizzle
// relocates 16-B slots within each row: u16 index ^= ((row & 7) << 3).
// Staging via global_load_lds writes LDS linearly, so the SOURCE slot is
// pre-swizzled with the same involution (rule #21: both-sides-or-neither).
// ---------------------------------------------------------------------------
__device__ __forceinline__ bf16x8 frag_swz(const u16* tile, int row, int col) {
  const int sw = (row & 7) << 3;
  const int base = row * 64 + col;
  bf16x4 lo = *(const bf16x4*)(tile + (base ^ sw));          // k = +0..3 (+16*0)
  bf16x4 hi = *(const bf16x4*)(tile + ((base + 16) ^ sw));   // k = +16..19
  return __builtin_shufflevector(lo, hi, 0, 1, 2, 3, 4, 5, 6, 7);
}

// ---------------------------------------------------------------------------
// cast_many: fp32 -> bf16, up to 4 arrays selected by blockIdx.y
// ---------------------------------------------------------------------------
__global__ __launch_bounds__(256) void cast_many(
    const float* __restrict__ i0, const float* __restrict__ i1,
    const float* __restrict__ i2, const float* __restrict__ i3,
    u16* __restrict__ o0, u16* __restrict__ o1,
    u16* __restrict__ o2, u16* __restrict__ o3, int n8)
{
  const int z = blockIdx.y;
  const float* in = z == 0 ? i0 : z == 1 ? i1 : z == 2 ? i2 : i3;
  u16* out = z == 0 ? o0 : z == 1 ? o1 : z == 2 ? o2 : o3;
  const int i = blockIdx.x * 256 + threadIdx.x;
  if (i >= n8) return;
  const float4* p = (const float4*)in + (size_t)i * 2;
  const float4 a = p[0], b = p[1];
  u16x8 o;
  o[0] = f2bf(a.x); o[1] = f2bf(a.y); o[2] = f2bf(a.z); o[3] = f2bf(a.w);
  o[4] = f2bf(b.x); o[5] = f2bf(b.y); o[6] = f2bf(b.z); o[7] = f2bf(b.w);
  ((u16x8*)out)[i] = o;
}

// ---------------------------------------------------------------------------
// gemm_core: acc = X[row0:+128] @ W[col0:+128]^T   (bf16, 128x128 tile, BK=64,
// 512 threads = 8 waves in 4x2 grid, wave tile 32x64, swizzled LDS)
// ---------------------------------------------------------------------------
__device__ __forceinline__ void gemm_core(
    const u16* __restrict__ X, const u16* __restrict__ W,
    u16* smem, int row0, int col0, f32x4 (&acc)[2][4])
{
  const int tid = threadIdx.x;
  const int w = tid >> 6, lane = tid & 63;
  const int l15 = lane & 15, l4 = lane >> 4;
  const int wr = w >> 1, wc = w & 1;

  auto stage = [&](int buf, int k0) {
    u16* dA = smem + buf * 8192;
    u16* dB = smem + 16384 + buf * 8192;
#pragma unroll
    for (int s = 0; s < 2; ++s) {
      const int c = s * 512 + w * 64 + lane;     // LDS chunk 0..1023
      const int r = c >> 3;
      const int cc = (c & 7) ^ (r & 7);          // pre-swizzled source slot
      gll16(X + (size_t)(row0 + r) * Dc + k0 + cc * 8, dA + (s * 512 + w * 64) * 8);
      gll16(W + (size_t)(col0 + r) * Dc + k0 + cc * 8, dB + (s * 512 + w * 64) * 8);
    }
  };

  stage(0, 0);
  __syncthreads();

  for (int kt = 0; kt < Dc / 64; ++kt) {
    const int cur = kt & 1;
    if (kt + 1 < Dc / 64) stage(cur ^ 1, (kt + 1) * 64);
    const u16* At = smem + cur * 8192;
    const u16* Bt = smem + 16384 + cur * 8192;
#pragma unroll
    for (int ks = 0; ks < 2; ++ks) {
      bf16x8 af[2], bfr[4];
#pragma unroll
      for (int m = 0; m < 2; ++m)
        af[m] = frag_swz(At, wr * 32 + m * 16 + l15, ks * 32 + l4 * 4);
#pragma unroll
      for (int n = 0; n < 4; ++n)
        bfr[n] = frag_swz(Bt, wc * 64 + n * 16 + l15, ks * 32 + l4 * 4);
#pragma unroll
      for (int m = 0; m < 2; ++m)
#pragma unroll
        for (int n = 0; n < 4; ++n)
          acc[m][n] = __builtin_amdgcn_mfma_f32_16x16x32_bf16(af[m], bfr[n], acc[m][n], 0, 0, 0);
    }
    __syncthreads();
  }
}

// ---------------------------------------------------------------------------
// gemm_qkv: fused Q/K/V projections (blockIdx.z selects). z=0,1 -> RoPE ->
// bf16 [B,H,S,DK]; z=2 -> V transposed -> bf16 [B,H,DK,S].
// ---------------------------------------------------------------------------
__global__ __launch_bounds__(512) void gemm_qkv(
    const u16* __restrict__ xq, const u16* __restrict__ xk, const u16* __restrict__ xv,
    const u16* __restrict__ wq, const u16* __restrict__ wk, const u16* __restrict__ wv,
    const float* __restrict__ bq, const float* __restrict__ bk, const float* __restrict__ bv,
    u16* __restrict__ Qb, u16* __restrict__ Kb, u16* __restrict__ Vt)
{
  __shared__ u16 smem[4 * 128 * 64];             // 64 KB
  const int z = blockIdx.z;
  const u16* X = z == 0 ? xq : z == 1 ? xk : xv;
  const u16* W = z == 0 ? wq : z == 1 ? wk : wv;
  const float* bias = z == 0 ? bq : z == 1 ? bk : bv;

  const int tid = threadIdx.x;
  const int w = tid >> 6, lane = tid & 63;
  const int l15 = lane & 15, l4 = lane >> 4;
  const int wr = w >> 1, wc = w & 1;
  const int row0 = blockIdx.x * 128;
  const int col0 = blockIdx.y * 128;

  f32x4 acc[2][4] = {};
  gemm_core(X, W, smem, row0, col0, acc);

  if (z < 2) {                                   // Q or K: +bias, RoPE, [B,H,S,DK]
    u16* Out = z == 0 ? Qb : Kb;
    const int h = (col0 >> 6) + wc;
#pragma unroll
    for (int m = 0; m < 2; ++m)
#pragma unroll
      for (int i = 0; i < 4; ++i) {
        const int row = row0 + wr * 32 + m * 16 + 4 * l4 + i;
        const int srow = row & (Sc - 1);
        const size_t obase = ((size_t)((row >> 11) * Hc + h) * Sc + srow) * DKc;
        float vv[4];
#pragma unroll
        for (int n = 0; n < 4; ++n)
          vv[n] = acc[m][n][i] + bias[col0 + wc * 64 + n * 16 + l15];
        float cs[2], sn[2];
#pragma unroll
        for (int hf = 0; hf < 2; ++hf) {
          const int jj = hf * 16 + l15;          // dk & 31
          const float ang = (float)srow * exp2f((float)jj * (-13.287712379549449f / 32.0f));
          sincosf(ang, &sn[hf], &cs[hf]);        // sin FIRST
        }
#pragma unroll
        for (int n = 0; n < 4; ++n) {
          const float rot = (n < 2) ? -vv[n ^ 2] : vv[n ^ 2];   // partner dk^32
          const float o = vv[n] * cs[n & 1] + rot * sn[n & 1];
          Out[obase + n * 16 + l15] = f2bf(o);
        }
      }
  } else {                                       // V -> [B,H,DK,S] via LDS transpose
    u16* T = smem;                               // [128 c][132 r]
    __syncthreads();
#pragma unroll
    for (int m = 0; m < 2; ++m)
#pragma unroll
      for (int i = 0; i < 4; ++i) {
        const int r = wr * 32 + m * 16 + 4 * l4 + i;
#pragma unroll
        for (int n = 0; n < 4; ++n) {
          const int c = wc * 64 + n * 16 + l15;
          T[c * 132 + r] = f2bf(acc[m][n][i] + bias[col0 + c]);
        }
      }
    __syncthreads();
    const int bidx = row0 >> 11, srow0 = row0 & (Sc - 1);
    const int c = tid >> 2, rq = (tid & 3) * 32;
    const int h = (col0 >> 6) + (c >> 6);
    const int dk = c & 63;
    u16* gdst = Vt + ((size_t)(bidx * Hc + h) * DKc + dk) * Sc + srow0 + rq;
#pragma unroll
    for (int u = 0; u < 4; ++u)
      *(u16x8*)(gdst + u * 8) = *(const u16x8*)&T[c * 132 + rq + u * 8];
  }
}

// ---------------------------------------------------------------------------
// gemm_out: out = Xb @ Wo^T + bo, fp32 [M][D]
// ---------------------------------------------------------------------------
__global__ __launch_bounds__(512) void gemm_out(
    const u16* __restrict__ X, const u16* __restrict__ W,
    const float* __restrict__ bias, float* __restrict__ Out)
{
  __shared__ u16 smem[4 * 128 * 64];
  const int tid = threadIdx.x;
  const int w = tid >> 6, lane = tid & 63;
  const int l15 = lane & 15, l4 = lane >> 4;
  const int wr = w >> 1, wc = w & 1;
  const int row0 = blockIdx.x * 128;
  const int col0 = blockIdx.y * 128;

  f32x4 acc[2][4] = {};
  gemm_core(X, W, smem, row0, col0, acc);

#pragma unroll
  for (int m = 0; m < 2; ++m)
#pragma unroll
    for (int i = 0; i < 4; ++i) {
      const int row = row0 + wr * 32 + m * 16 + 4 * l4 + i;
#pragma unroll
      for (int n = 0; n < 4; ++n) {
        const int col = col0 + wc * 64 + n * 16 + l15;
        Out[(size_t)row * Dc + col] = acc[m][n][i] + bias[col];
      }
    }
}

// ---------------------------------------------------------------------------
// attn_mfma: causal flash attention, bf16 MFMA. QBLK=128 (4 waves x 32 rows),
// KVBLK=64, double-buffered K/V staging, swizzled LDS everywhere.
// Q,K: [B,H,S,64] bf16; Vt: [B,H,64,S] bf16; out Xb: [B,S,1024] bf16.
// ---------------------------------------------------------------------------
__global__ __launch_bounds__(256) void attn_mfma(
    const u16* __restrict__ Qb, const u16* __restrict__ Kb,
    const u16* __restrict__ Vt, u16* __restrict__ Xb)
{
  __shared__ u16 smem[32768];                    // 64 KB
  // Qs [128][64] @0; K bufs @8192+buf*4096; V bufs @16384+buf*4096; Ps @24576
  u16* Qs = smem;
  u16* Ps = smem + 24576;

  const int tid = threadIdx.x;
  const int w = tid >> 6, lane = tid & 63;
  const int l15 = lane & 15, l4 = lane >> 4;
  const int qt = gridDim.x - 1 - blockIdx.x;     // heavy q-tiles first
  const int bh = blockIdx.y;
  const int q0 = qt * 128;
  const u16* Qg = Qb + ((size_t)bh * Sc + q0) * DKc;
  const u16* Kg = Kb + (size_t)bh * Sc * DKc;
  const u16* Vg = Vt + (size_t)bh * DKc * Sc;

  // stage Q (1024 chunks, swizzled source)
#pragma unroll
  for (int s = 0; s < 4; ++s) {
    const int c = s * 256 + w * 64 + lane;
    const int r = c >> 3;
    const int cc = (c & 7) ^ (r & 7);
    gll16(Qg + (size_t)r * DKc + cc * 8, Qs + (s * 256 + w * 64) * 8);
  }
  auto stageKV = [&](int buf, int k0) {
    u16* Kd = smem + 8192 + buf * 4096;
    u16* Vd = smem + 16384 + buf * 4096;
#pragma unroll
    for (int s = 0; s < 2; ++s) {
      const int c = s * 256 + w * 64 + lane;     // 0..511
      const int r = c >> 3;
      const int cc = (c & 7) ^ (r & 7);
      gll16(Kg + (size_t)(k0 + r) * DKc + cc * 8, Kd + (s * 256 + w * 64) * 8);
      gll16(Vg + (size_t)r * Sc + k0 + cc * 8,   Vd + (s * 256 + w * 64) * 8);
    }
  };
  stageKV(0, 0);
  __syncthreads();

  f32x4 aco[2][4] = {};
  float mrow[2][4], lrow[2][4];
#pragma unroll
  for (int m = 0; m < 2; ++m)
#pragma unroll
    for (int i = 0; i < 4; ++i) { mrow[m][i] = -INFINITY; lrow[m][i] = 0.f; }

  const int nk = 2 * qt + 2;
  for (int kt = 0; kt < nk; ++kt) {
    const int cur = kt & 1;
    if (kt + 1 < nk) stageKV(cur ^ 1, (kt + 1) * 64);
    const u16* Kt = smem + 8192 + cur * 4096;
    const u16* Vc = smem + 16384 + cur * 4096;

    // S = Q K^T (wave's 32 q-rows x 64 k-cols)
    f32x4 acs[2][4] = {};
#pragma unroll
    for (int ks = 0; ks < 2; ++ks) {
      bf16x8 aq[2], bk[4];
#pragma unroll
      for (int m = 0; m < 2; ++m)
        aq[m] = frag_swz(Qs, w * 32 + m * 16 + l15, ks * 32 + l4 * 4);
#pragma unroll
      for (int n = 0; n < 4; ++n)
        bk[n] = frag_swz(Kt, n * 16 + l15, ks * 32 + l4 * 4);
#pragma unroll
      for (int m = 0; m < 2; ++m)
#pragma unroll
        for (int n = 0; n < 4; ++n)
          acs[m][n] = __builtin_amdgcn_mfma_f32_16x16x32_bf16(aq[m], bk[n], acs[m][n], 0, 0, 0);
    }

    // online softmax (rows: q = q0 + w*32 + m*16 + 4*l4 + i; cols: n*16 + l15)
    const bool mtile = (kt >= 2 * qt);
    const int k0 = kt * 64;
#pragma unroll
    for (int m = 0; m < 2; ++m)
#pragma unroll
      for (int i = 0; i < 4; ++i) {
        const int q = q0 + w * 32 + m * 16 + 4 * l4 + i;
        float sv[4], rm = -INFINITY;
#pragma unroll
        for (int n = 0; n < 4; ++n) {
          sv[n] = acs[m][n][i] * 0.125f;
          if (mtile && (k0 + n * 16 + l15) > q) sv[n] = -1e9f;
          rm = fmaxf(rm, sv[n]);
        }
#pragma unroll
        for (int off = 1; off < 16; off <<= 1) rm = fmaxf(rm, __shfl_xor(rm, off, 64));
        const float mnew = fmaxf(mrow[m][i], rm);
        const float corr = __expf(mrow[m][i] - mnew);
        mrow[m][i] = mnew;
        float p[4], rs = 0.f;
#pragma unroll
        for (int n = 0; n < 4; ++n) { p[n] = __expf(sv[n] - mnew); rs += p[n]; }
#pragma unroll
        for (int off = 1; off < 16; off <<= 1) rs += __shfl_xor(rs, off, 64);
        lrow[m][i] = lrow[m][i] * corr + rs;
        const int prow = w * 32 + m * 16 + 4 * l4 + i;
        const int psw = (prow & 7) << 3;
#pragma unroll
        for (int n = 0; n < 4; ++n) {
          aco[m][n][i] *= corr;
          Ps[(prow * 64 + n * 16 + l15) ^ psw] = f2bf(p[n]);   // swizzled write
        }
      }

    // O += P V
#pragma unroll
    for (int ks = 0; ks < 2; ++ks) {
      bf16x8 pa[2], bv[4];
#pragma unroll
      for (int m = 0; m < 2; ++m)
        pa[m] = frag_swz(Ps, w * 32 + m * 16 + l15, ks * 32 + l4 * 4);
#pragma unroll
      for (int n = 0; n < 4; ++n)
        bv[n] = frag_swz(Vc, n * 16 + l15, ks * 32 + l4 * 4);
#pragma unroll
      for (int m = 0; m < 2; ++m)
#pragma unroll
        for (int n = 0; n < 4; ++n)
          aco[m][n] = __builtin_amdgcn_mfma_f32_16x16x32_bf16(pa[m], bv[n], aco[m][n], 0, 0, 0);
    }
    __syncthreads();
  }

  // epilogue: x[b, q, h*64+dk] = O/l
  const int bidx = bh >> 4, h = bh & 15;
#pragma unroll
  for (int m = 0; m < 2; ++m)
#pragma unroll
    for (int i = 0; i < 4; ++i) {
      const int q = q0 + w * 32 + m * 16 + 4 * l4 + i;
      const float inv = 1.0f / lrow[m][i];
#pragma unroll
      for (int n = 0; n < 4; ++n)
        Xb[((size_t)bidx * Sc + q) * Dc + h * DKc + n * 16 + l15] = f2bf(aco[m][n][i] * inv);
    }
}

// ---------------------------------------------------------------------------
extern "C" void kernel_launch(void* const* d_in, const int* in_sizes, int n_in,
                              void* d_out, int out_size, void* d_ws, size_t ws_size,
                              hipStream_t stream) {
  const float* query = (const float*)d_in[0];
  const float* key   = (const float*)d_in[1];
  const float* value = (const float*)d_in[2];
  const float* Wq = (const float*)d_in[4];
  const float* bq = (const float*)d_in[5];
  const float* Wk = (const float*)d_in[6];
  const float* bk = (const float*)d_in[7];
  const float* Wv = (const float*)d_in[8];
  const float* bv = (const float*)d_in[9];
  const float* Wo = (const float*)d_in[10];
  const float* bo = (const float*)d_in[11];

  const size_t MD = (size_t)Mc * Dc;   // 4M
  const size_t DD = (size_t)Dc * Dc;   // 1M
  u16* xq = (u16*)d_ws;
  u16* xk = xq + MD;
  u16* xv = xk + MD;
  u16* wq = xv + MD;
  u16* wk = wq + DD;
  u16* wv = wk + DD;
  u16* wo = wv + DD;
  u16* Qb = wo + DD;
  u16* Kb = Qb + MD;
  u16* Vt = Kb + MD;
  u16* Xb = Vt + MD;   // total 64 MB

  cast_many<<<dim3(MD / 2048, 3), 256, 0, stream>>>(
      query, key, value, nullptr, xq, xk, xv, nullptr, (int)(MD / 8));
  cast_many<<<dim3(DD / 2048, 4), 256, 0, stream>>>(
      Wq, Wk, Wv, Wo, wq, wk, wv, wo, (int)(DD / 8));

  gemm_qkv<<<dim3(Mc / 128, Dc / 128, 3), 512, 0, stream>>>(
      xq, xk, xv, wq, wk, wv, bq, bk, bv, Qb, Kb, Vt);
  attn_mfma<<<dim3(Sc / 128, Bc * Hc), 256, 0, stream>>>(Qb, Kb, Vt, Xb);
  gemm_out<<<dim3(Mc / 128, Dc / 128), 512, 0, stream>>>(Xb, wo, bo, (float*)d_out);
}